// Round 18
// baseline (787.965 us; speedup 1.0000x reference)
//
#include <hip/hip_runtime.h>
#include <hip/hip_cooperative_groups.h>
#include <math.h>

namespace cg = cooperative_groups;

#define NSLOPE 0.2f
#define BSH 8                  // 256 nodes per scatter stream-bucket
#define BNODES 256
#define NID_MASK 0x1FFFF       // node id fits 17 bits
#define SENT 0xFFFFFFFFu
#define CAP 10240              // per-stream region capacity
#define NSMAX 800              // max streams
#define BN9 512                // layer-1 super-bucket nodes
#define LCAP 17408             // LDS list capacity (records)
#define CPP9 9                 // pairs per thread (ceil(LCAP/2/1024))
#define TPB 1024
// fused-scatter params
#define FRE 5120
#define FEPT 5
#define FSLOT 20               // mean 13.1/stream/round
#define FSPILL 256
#define AUXN (2 * NSMAX + 3 * FSPILL + 2)
// fallback-scatter params (r16 proven)
#define GB 768
#define RE 2560
#define EPT 5
#define SLOT 12
#define SPILLCAP 256

__device__ __forceinline__ float lrelu(float v) { return v > 0.f ? v : NSLOPE * v; }

// ---------------------------------------------------------------- node prep
__global__ void k_prep(const float* __restrict__ x,
                       const float* __restrict__ as1, const float* __restrict__ ad1,
                       const float* __restrict__ as1r, const float* __restrict__ ad1r,
                       const float* __restrict__ W1, const float* __restrict__ W1r,
                       float4* __restrict__ rec4f, float4* __restrict__ rec4r,
                       float* __restrict__ s1df, float* __restrict__ s1dr,
                       int* __restrict__ gcur, int NS, int N) {
    int i = blockIdx.x * blockDim.x + threadIdx.x;
    if (i < NS) gcur[i] = 0;
    if (i >= N) return;
    float x0 = x[3 * i], x1 = x[3 * i + 1], x2 = x[3 * i + 2];
    float ssf = 0.f, sdf = 0.f, ssr = 0.f, sdr = 0.f;
#pragma unroll
    for (int k = 0; k < 16; k++) {
        float hf = x0 * W1[k] + x1 * W1[16 + k] + x2 * W1[32 + k];
        ssf += hf * as1[k];
        sdf += hf * ad1[k];
        float hr = x0 * W1r[k] + x1 * W1r[16 + k] + x2 * W1r[32 + k];
        ssr += hr * as1r[k];
        sdr += hr * ad1r[k];
    }
    rec4f[i] = make_float4(x0, x1, x2, ssf);
    rec4r[i] = make_float4(x0, x1, x2, ssr);
    s1df[i] = sdf; s1dr[i] = sdr;
}

// ================================================================ FUSED PATH
struct FP {
    const void* ei; long long E;
    int NB8, NS, N;
    int* gcur; unsigned* bin;
    const float4* rec4f; const float* s1df;
    const float4* rec4r; const float* s1dr;
    const float *b1, *W1, *W2, *as2, *ad2;
    const float *b1r, *W1r, *W2r, *as2r, *ad2r;
    const float *b2, *b2r;
    float2 *p2f, *p2r; float *s2df, *s2dr;
    float* res; float* out;
};

__global__ void __launch_bounds__(TPB, 8) k_fused(FP p) {
    cg::grid_group grid = cg::this_grid();
    __shared__ unsigned s_big[LCAP];
    __shared__ int s_aux[AUXN];
    __shared__ int flagsm;
    int t = threadIdx.x;
    int bid = blockIdx.x;
    int GRID = gridDim.x;

    // ---- phase 1: scatter into bucket streams
    {
        unsigned* strips = s_big;
        int* scnt  = s_aux;
        int* sgpos = s_aux + NSMAX;
        int* sps   = s_aux + 2 * NSMAX;
        int* spp   = sps + FSPILL;
        unsigned* spr = (unsigned*)(spp + FSPILL);
        int* spn   = (int*)(spr + FSPILL);

        if (t < 64) {
            const unsigned long long* q = (const unsigned long long*)p.ei;
            bool bad = false;
#pragma unroll
            for (int i = 0; i < 4; i++)
                if (q[t * 4 + i] >= (1ull << 32)) bad = true;
            unsigned long long mask = __ballot(bad);
            if (t == 0) flagsm = (mask == 0ull) ? 1 : 0;
        }
        __syncthreads();
        int fl = flagsm;
        long long chunk = (p.E + GRID - 1) / GRID;
        long long cstart = (long long)bid * chunk;
        long long cend = cstart + chunk; if (cend > p.E) cend = p.E;

        for (long long rs = cstart; rs < cend; rs += FRE) {
            int ne = (int)min((long long)FRE, cend - rs);
            for (int c = t; c < p.NS; c += TPB) scnt[c] = 0;
            if (t == 0) *spn = 0;
            int eu[FEPT], ev[FEPT];
#pragma unroll
            for (int k = 0; k < FEPT; k++) {
                int idx = t + k * TPB;
                eu[k] = -1;
                if (idx < ne) {
                    long long i = rs + idx;
                    if (fl) { const long long* q = (const long long*)p.ei;
                              eu[k] = (int)q[i]; ev[k] = (int)q[p.E + i]; }
                    else    { const int* q = (const int*)p.ei;
                              eu[k] = q[i]; ev[k] = q[p.E + i]; }
                }
            }
            __syncthreads();
#pragma unroll
            for (int k = 0; k < FEPT; k++) {
                if (eu[k] >= 0) {
                    int u = eu[k], v = ev[k];
                    unsigned r0 = (unsigned)u | ((unsigned)(v & (BNODES - 1)) << 17);
                    int s0 = v >> BSH;
                    unsigned r1 = (unsigned)v | ((unsigned)(u & (BNODES - 1)) << 17);
                    int s1 = p.NB8 + (u >> BSH);
                    int p0 = atomicAdd(&scnt[s0], 1);
                    if (p0 < FSLOT) strips[s0 * FSLOT + p0] = r0;
                    else { int sp = atomicAdd(spn, 1); if (sp < FSPILL) { sps[sp] = s0; spp[sp] = p0; spr[sp] = r0; } }
                    int p1 = atomicAdd(&scnt[s1], 1);
                    if (p1 < FSLOT) strips[s1 * FSLOT + p1] = r1;
                    else { int sp = atomicAdd(spn, 1); if (sp < FSPILL) { sps[sp] = s1; spp[sp] = p1; spr[sp] = r1; } }
                }
            }
            __syncthreads();
            for (int c = t; c < p.NS; c += TPB) {
                int n = scnt[c];
                sgpos[c] = n ? atomicAdd(&p.gcur[c], n) : 0;
            }
            __syncthreads();
            for (int c = t; c < p.NS; c += TPB) {
                int n = scnt[c];
                if (!n) continue;
                int g = sgpos[c];
                long long b = (long long)c * CAP;
                int m = n < FSLOT ? n : FSLOT;
                if (g + n <= CAP) {
                    int j = 0;
                    if (g & 1) { p.bin[b + g] = strips[c * FSLOT]; j = 1; }
                    for (; j + 2 <= m; j += 2)
                        *(uint2*)(p.bin + b + g + j) =
                            make_uint2(strips[c * FSLOT + j], strips[c * FSLOT + j + 1]);
                    if (j < m) p.bin[b + g + j] = strips[c * FSLOT + j];
                }
            }
            int nsp = *spn; if (nsp > FSPILL) nsp = FSPILL;
            for (int i = t; i < nsp; i += TPB) {
                int s = sps[i];
                int off = sgpos[s] + spp[i];
                if (off < CAP) p.bin[(long long)s * CAP + off] = spr[i];
            }
            __syncthreads();
        }
    }
    __threadfence();
    grid.sync();

    // ---- phase 2: layer-1 sort + aggregate
    unsigned* lds_u = s_big;
    int* cnt  = s_aux;
    int* loff = s_aux + BN9;
    int* segtot = s_aux + 2 * BN9;

    int dir = bid & 1, bb = bid >> 1;
    const float4* rec4 = dir ? p.rec4r : p.rec4f;
    const float* s1d = dir ? p.s1dr : p.s1df;
    const float* b1_ = dir ? p.b1r : p.b1;
    const float* W1_ = dir ? p.W1r : p.W1;
    const float* W2_ = dir ? p.W2r : p.W2;
    float as2v = dir ? p.as2r[0] : p.as2[0];
    float ad2v = dir ? p.ad2r[0] : p.ad2[0];
    float2* p2 = dir ? p.p2r : p.p2f;
    float* s2d = dir ? p.s2dr : p.s2df;

    int c0 = dir * p.NB8 + 2 * bb;
    bool c1ok = (2 * bb + 1) < p.NB8;
    long long base = (long long)c0 * CAP;
    int n0 = p.gcur[c0]; if (n0 > CAP) n0 = CAP;
    int n1 = c1ok ? p.gcur[c0 + 1] : 0; if (n1 > CAP) n1 = CAP;
    int np0 = (n0 + 1) >> 1, np1 = (n1 + 1) >> 1;
    if (np0 > LCAP / 2) np0 = LCAP / 2;
    if (np0 + np1 > LCAP / 2) np1 = LCAP / 2 - np0;
    int nptot = np0 + np1;
    int v0 = bb << 9;
    int nv = p.N - v0; if (nv > BN9) nv = BN9;

    const uint2* bp0 = (const uint2*)(p.bin + base);
    const uint2* bp1 = (const uint2*)(p.bin + base) + CAP / 2;
    uint2 recs[CPP9];
#pragma unroll
    for (int k = 0; k < CPP9; k++) {
        int i = t + k * TPB;
        uint2 r = make_uint2(SENT, SENT);
        if (i < np0) {
            r = bp0[i];
            if (2 * i + 1 >= n0) r.y = SENT;
        } else if (i < nptot) {
            int i1 = i - np0;
            r = bp1[i1];
            if (2 * i1 + 1 >= n1) r.y = SENT;
            r.x += (256u << 17);
            if (r.y != SENT) r.y += (256u << 17);
        }
        recs[k] = r;
    }
    if (t < BN9) cnt[t] = 0;
    __syncthreads();
#pragma unroll
    for (int k = 0; k < CPP9; k++) {
        if (recs[k].x != SENT) atomicAdd(&cnt[recs[k].x >> 17], 1);
        if (recs[k].y != SENT) atomicAdd(&cnt[recs[k].y >> 17], 1);
    }
    __syncthreads();
    if (t < BN9) {
        int lane = t & 63, wv = t >> 6;
        int val = cnt[t];
        int incl = val;
#pragma unroll
        for (int od = 1; od < 64; od <<= 1) {
            int up = __shfl_up(incl, od);
            if (lane >= od) incl += up;
        }
        if (lane == 63) segtot[wv] = incl;
        loff[t] = incl - val;
    }
    __syncthreads();
    if (t < BN9) {
        int wv = t >> 6;
        int offs = 0;
#pragma unroll
        for (int j = 0; j < 8; j++) offs += (j < wv) ? segtot[j] : 0;
        int ex = loff[t] + offs;
        loff[t] = ex;
        cnt[t] = ex;
    }
    __syncthreads();
#pragma unroll
    for (int k = 0; k < CPP9; k++) {
        if (recs[k].x != SENT) {
            int q = atomicAdd(&cnt[recs[k].x >> 17], 1);
            lds_u[q] = recs[k].x & NID_MASK;
        }
        if (recs[k].y != SENT) {
            int q = atomicAdd(&cnt[recs[k].y >> 17], 1);
            lds_u[q] = recs[k].y & NID_MASK;
        }
    }
    __syncthreads();
    int node = t >> 1, lane = t & 1;
    float sdv = (node < nv) ? s1d[v0 + node] : 0.f;
    {
        float d = 0.f, a0 = 0.f, a1 = 0.f, a2 = 0.f;
        if (node < nv) {
            int ls = loff[node], le = cnt[node];
            for (int pos = ls + lane; pos < le; pos += 2) {
                unsigned u = lds_u[pos];
                float4 r = rec4[u];
                float w = __expf(lrelu(r.w + sdv));
                d += w; a0 += w * r.x; a1 += w * r.y; a2 += w * r.z;
            }
        }
        d  += __shfl_xor(d, 1);
        a0 += __shfl_xor(a0, 1);
        a1 += __shfl_xor(a1, 1);
        a2 += __shfl_xor(a2, 1);
        if (lane == 0 && node < nv) {
            int v = v0 + node;
            float4 r = rec4[v];
            float w = __expf(lrelu(r.w + sdv));
            float dd = d + w;
            float inv = 1.f / (dd + 1e-16f);
            float m0 = (a0 + w * r.x) * inv;
            float m1 = (a1 + w * r.y) * inv;
            float m2 = (a2 + w * r.z) * inv;
            float h2v = 0.f;
#pragma unroll
            for (int k = 0; k < 16; k++) {
                float o = m0 * W1_[k] + m1 * W1_[16 + k] + m2 * W1_[32 + k] + b1_[k];
                o = fmaxf(o, 0.f);
                h2v += o * W2_[k];
            }
            p2[v] = make_float2(h2v, h2v * as2v);
            s2d[v] = h2v * ad2v;
        }
    }
    __threadfence();
    grid.sync();

    // ---- phase 3: layer-2 from LDS-resident lists
    {
        float bias = dir ? p.b2r[0] : p.b2[0];
        float sd2 = (node < nv) ? s2d[v0 + node] : 0.f;
        float d = 0.f, a = 0.f;
        if (node < nv) {
            int ls = loff[node], le = cnt[node];
            for (int pos = ls + lane; pos < le; pos += 2) {
                unsigned u = lds_u[pos];
                float2 r = p2[u];
                float w = __expf(lrelu(r.y + sd2));
                d += w; a += w * r.x;
            }
        }
        d += __shfl_xor(d, 1);
        a += __shfl_xor(a, 1);
        if (lane == 0 && node < nv) {
            int v = v0 + node;
            float2 r = p2[v];
            float w = __expf(lrelu(r.y + sd2));
            p.res[dir * p.N + v] = (a + w * r.x) / (d + w + 1e-16f) + bias;
        }
    }
    __threadfence();
    grid.sync();

    // ---- phase 4: combine
    for (int i = bid * TPB + t; i < p.N; i += GRID * TPB)
        p.out[i] = 0.5f * (p.res[i] + p.res[p.N + i]);
}

// ================================================================ FALLBACK PATH (r16)
__global__ void __launch_bounds__(512) k_scatsort(
        const void* __restrict__ ei, long long E,
        int NB, int NS, int* __restrict__ gcur, unsigned* __restrict__ bin) {
    extern __shared__ unsigned smem[];
    unsigned* slots = smem;
    int* cnt  = (int*)(slots + (size_t)NS * SLOT);
    int* gpos = cnt + NS;
    int* spill_s = gpos + NS;
    int* spill_p = spill_s + SPILLCAP;
    unsigned* spill_r = (unsigned*)(spill_p + SPILLCAP);
    int* spn = (int*)(spill_r + SPILLCAP);
    __shared__ int flagsm;

    int t = threadIdx.x;
    if (t < 64) {
        const unsigned long long* p = (const unsigned long long*)ei;
        bool bad = false;
#pragma unroll
        for (int i = 0; i < 4; i++)
            if (p[t * 4 + i] >= (1ull << 32)) bad = true;
        unsigned long long mask = __ballot(bad);
        if (t == 0) flagsm = (mask == 0ull) ? 1 : 0;
    }
    __syncthreads();
    int fl = flagsm;
    long long chunk = (E + GB - 1) / GB;
    long long cstart = (long long)blockIdx.x * chunk;
    long long cend = cstart + chunk; if (cend > E) cend = E;

    for (long long rs = cstart; rs < cend; rs += RE) {
        int ne = (int)min((long long)RE, cend - rs);
        for (int c = t; c < NS; c += 512) cnt[c] = 0;
        if (t == 0) *spn = 0;
        int eu[EPT], ev[EPT];
#pragma unroll
        for (int k = 0; k < EPT; k++) {
            int idx = t + k * 512;
            eu[k] = -1;
            if (idx < ne) {
                long long i = rs + idx;
                if (fl) { const long long* p = (const long long*)ei;
                          eu[k] = (int)p[i]; ev[k] = (int)p[E + i]; }
                else    { const int* p = (const int*)ei;
                          eu[k] = p[i]; ev[k] = p[E + i]; }
            }
        }
        __syncthreads();
#pragma unroll
        for (int k = 0; k < EPT; k++) {
            if (eu[k] >= 0) {
                int u = eu[k], v = ev[k];
                unsigned r0 = (unsigned)u | ((unsigned)(v & (BNODES - 1)) << 17);
                int s0 = v >> BSH;
                unsigned r1 = (unsigned)v | ((unsigned)(u & (BNODES - 1)) << 17);
                int s1 = NB + (u >> BSH);
                int p0 = atomicAdd(&cnt[s0], 1);
                if (p0 < SLOT) slots[s0 * SLOT + p0] = r0;
                else { int sp = atomicAdd(spn, 1); if (sp < SPILLCAP) { spill_s[sp] = s0; spill_p[sp] = p0; spill_r[sp] = r0; } }
                int p1 = atomicAdd(&cnt[s1], 1);
                if (p1 < SLOT) slots[s1 * SLOT + p1] = r1;
                else { int sp = atomicAdd(spn, 1); if (sp < SPILLCAP) { spill_s[sp] = s1; spill_p[sp] = p1; spill_r[sp] = r1; } }
            }
        }
        __syncthreads();
        for (int c = t; c < NS; c += 512) {
            int n = cnt[c];
            gpos[c] = n ? atomicAdd(&gcur[c], n) : 0;
        }
        __syncthreads();
        for (int c = t; c < NS; c += 512) {
            int n = cnt[c];
            if (!n) continue;
            int g = gpos[c];
            long long b = (long long)c * CAP;
            int m = n < SLOT ? n : SLOT;
            if (g + n <= CAP) {
                int j = 0;
                if (g & 1) { bin[b + g] = slots[c * SLOT]; j = 1; }
                for (; j + 2 <= m; j += 2)
                    *(uint2*)(bin + b + g + j) =
                        make_uint2(slots[c * SLOT + j], slots[c * SLOT + j + 1]);
                if (j < m) bin[b + g + j] = slots[c * SLOT + j];
            }
        }
        int nsp = *spn; if (nsp > SPILLCAP) nsp = SPILLCAP;
        for (int i = t; i < nsp; i += 512) {
            int s = spill_s[i];
            int off = gpos[s] + spill_p[i];
            if (off < CAP) bin[(long long)s * CAP + off] = spill_r[i];
        }
        __syncthreads();
    }
}

__global__ void __launch_bounds__(TPB, 8) k_bagg1(
        unsigned* __restrict__ bin, const int* __restrict__ gcur,
        const float4* __restrict__ rec4f, const float* __restrict__ s1df,
        const float4* __restrict__ rec4r, const float* __restrict__ s1dr,
        const float* __restrict__ b1, const float* __restrict__ W1,
        const float* __restrict__ W2,
        const float* __restrict__ as2, const float* __restrict__ ad2,
        const float* __restrict__ b1r, const float* __restrict__ W1r,
        const float* __restrict__ W2r,
        const float* __restrict__ as2r, const float* __restrict__ ad2r,
        float2* __restrict__ p2f, float* __restrict__ s2df,
        float2* __restrict__ p2r, float* __restrict__ s2dr,
        int* __restrict__ aoff, int* __restrict__ aend, int NB8, int N) {
    int bb = blockIdx.x, dir = blockIdx.y;
    const float4* rec4 = dir ? rec4r : rec4f;
    const float* s1d = dir ? s1dr : s1df;
    const float* b1_ = dir ? b1r : b1;
    const float* W1_ = dir ? W1r : W1;
    const float* W2_ = dir ? W2r : W2;
    float as2v = dir ? as2r[0] : as2[0];
    float ad2v = dir ? ad2r[0] : ad2[0];
    float2* p2 = dir ? p2r : p2f;
    float* s2d = dir ? s2dr : s2df;

    int c0 = dir * NB8 + 2 * bb;
    bool c1ok = (2 * bb + 1) < NB8;
    long long base = (long long)c0 * CAP;
    int n0 = gcur[c0]; if (n0 > CAP) n0 = CAP;
    int n1 = c1ok ? gcur[c0 + 1] : 0; if (n1 > CAP) n1 = CAP;
    int np0 = (n0 + 1) >> 1, np1 = (n1 + 1) >> 1;
    if (np0 > LCAP / 2) np0 = LCAP / 2;
    if (np0 + np1 > LCAP / 2) np1 = LCAP / 2 - np0;
    int nptot = np0 + np1;
    int v0 = bb << 9;
    int nv = N - v0; if (nv > BN9) nv = BN9;

    __shared__ int cnt[BN9];
    __shared__ int loff[BN9];
    __shared__ int segtot[8];
    __shared__ unsigned lds_u[LCAP];
    int t = threadIdx.x;

    const uint2* bp0 = (const uint2*)(bin + base);
    const uint2* bp1 = (const uint2*)(bin + base) + CAP / 2;
    uint2 recs[CPP9];
#pragma unroll
    for (int k = 0; k < CPP9; k++) {
        int i = t + k * TPB;
        uint2 r = make_uint2(SENT, SENT);
        if (i < np0) {
            r = bp0[i];
            if (2 * i + 1 >= n0) r.y = SENT;
        } else if (i < nptot) {
            int i1 = i - np0;
            r = bp1[i1];
            if (2 * i1 + 1 >= n1) r.y = SENT;
            r.x += (256u << 17);
            if (r.y != SENT) r.y += (256u << 17);
        }
        recs[k] = r;
    }
    if (t < BN9) cnt[t] = 0;
    __syncthreads();
#pragma unroll
    for (int k = 0; k < CPP9; k++) {
        if (recs[k].x != SENT) atomicAdd(&cnt[recs[k].x >> 17], 1);
        if (recs[k].y != SENT) atomicAdd(&cnt[recs[k].y >> 17], 1);
    }
    __syncthreads();
    if (t < BN9) {
        int lane = t & 63, wv = t >> 6;
        int val = cnt[t];
        int incl = val;
#pragma unroll
        for (int od = 1; od < 64; od <<= 1) {
            int up = __shfl_up(incl, od);
            if (lane >= od) incl += up;
        }
        if (lane == 63) segtot[wv] = incl;
        loff[t] = incl - val;
    }
    __syncthreads();
    if (t < BN9) {
        int wv = t >> 6;
        int offs = 0;
#pragma unroll
        for (int j = 0; j < 8; j++) offs += (j < wv) ? segtot[j] : 0;
        int ex = loff[t] + offs;
        loff[t] = ex;
        cnt[t] = ex;
    }
    __syncthreads();
#pragma unroll
    for (int k = 0; k < CPP9; k++) {
        if (recs[k].x != SENT) {
            int q = atomicAdd(&cnt[recs[k].x >> 17], 1);
            lds_u[q] = recs[k].x & NID_MASK;
        }
        if (recs[k].y != SENT) {
            int q = atomicAdd(&cnt[recs[k].y >> 17], 1);
            lds_u[q] = recs[k].y & NID_MASK;
        }
    }
    __syncthreads();
    int node = t >> 1, lane = t & 1;
    float sdv = (node < nv) ? s1d[v0 + node] : 0.f;
    float d = 0.f, a0 = 0.f, a1 = 0.f, a2 = 0.f;
    if (node < nv) {
        int ls = loff[node], le = cnt[node];
        for (int pos = ls + lane; pos < le; pos += 2) {
            unsigned u = lds_u[pos];
            float4 r = rec4[u];
            float w = __expf(lrelu(r.w + sdv));
            d += w; a0 += w * r.x; a1 += w * r.y; a2 += w * r.z;
        }
    }
    d  += __shfl_xor(d, 1);
    a0 += __shfl_xor(a0, 1);
    a1 += __shfl_xor(a1, 1);
    a2 += __shfl_xor(a2, 1);
    if (lane == 0 && node < nv) {
        int v = v0 + node;
        float4 r = rec4[v];
        float w = __expf(lrelu(r.w + sdv));
        float dd = d + w;
        float inv = 1.f / (dd + 1e-16f);
        float m0 = (a0 + w * r.x) * inv;
        float m1 = (a1 + w * r.y) * inv;
        float m2 = (a2 + w * r.z) * inv;
        float h2v = 0.f;
#pragma unroll
        for (int k = 0; k < 16; k++) {
            float o = m0 * W1_[k] + m1 * W1_[16 + k] + m2 * W1_[32 + k] + b1_[k];
            o = fmaxf(o, 0.f);
            h2v += o * W2_[k];
        }
        p2[v] = make_float2(h2v, h2v * as2v);
        s2d[v] = h2v * ad2v;
    }
    int nreal = (nv > 0) ? cnt[nv - 1] : 0;
    if (t == 0 && (nreal & 1)) lds_u[nreal] = SENT;
    __syncthreads();
    int ndp = (nreal + 1) >> 1;
    uint2* bq = (uint2*)(bin + base);
    for (int i = t; i < ndp; i += TPB)
        bq[i] = make_uint2(lds_u[2 * i], lds_u[2 * i + 1]);
    if (t < nv) {
        aoff[dir * N + v0 + t] = (int)(base + loff[t]);
        aend[dir * N + v0 + t] = (int)(base + cnt[t]);
    }
}

__global__ void k_agg2(const unsigned* __restrict__ bin,
                       const int* __restrict__ aoff, const int* __restrict__ aend,
                       const float2* __restrict__ p2f, const float* __restrict__ s2df,
                       const float2* __restrict__ p2r, const float* __restrict__ s2dr,
                       const float* __restrict__ b2, const float* __restrict__ b2r,
                       float* __restrict__ out, int N) {
    int tid = blockIdx.x * blockDim.x + threadIdx.x;
    int v = tid >> 4;
    int lane = tid & 15;
    if (v >= N) return;
    float res[2];
#pragma unroll
    for (int dir = 0; dir < 2; dir++) {
        const float2* p2 = dir ? p2r : p2f;
        const float* s2d = dir ? s2dr : s2df;
        float bias = dir ? b2r[0] : b2[0];
        float sd = s2d[v];
        int st = aoff[dir * N + v], en = aend[dir * N + v];
        float d = 0.f, a = 0.f;
        if (lane == 0) {
            float2 ts = p2[v];
            float w = __expf(lrelu(ts.y + sd));
            d = w; a = w * ts.x;
        }
        int j = st + lane;
        for (; j + 16 < en; j += 32) {
            unsigned u0 = __builtin_nontemporal_load(bin + j);
            unsigned u1 = __builtin_nontemporal_load(bin + j + 16);
            float2 t0 = p2[u0];
            float2 t1 = p2[u1];
            float w0 = __expf(lrelu(t0.y + sd));
            float w1 = __expf(lrelu(t1.y + sd));
            d += w0 + w1;
            a += w0 * t0.x + w1 * t1.x;
        }
        for (; j < en; j += 16) {
            unsigned u = __builtin_nontemporal_load(bin + j);
            float2 t = p2[u];
            float w = __expf(lrelu(t.y + sd));
            d += w;
            a += w * t.x;
        }
#pragma unroll
        for (int mask = 1; mask < 16; mask <<= 1) {
            d += __shfl_xor(d, mask);
            a += __shfl_xor(a, mask);
        }
        res[dir] = a / (d + 1e-16f) + bias;
    }
    if (lane == 0) out[v] = 0.5f * (res[0] + res[1]);
}

// ================================================================ launch
extern "C" void kernel_launch(void* const* d_in, const int* in_sizes, int n_in,
                              void* d_out, int out_size, void* d_ws, size_t ws_size,
                              hipStream_t stream) {
    const float* x   = (const float*)d_in[0];
    const void*  ei  = d_in[1];
    const float* W1  = (const float*)d_in[2];
    const float* as1 = (const float*)d_in[3];
    const float* ad1 = (const float*)d_in[4];
    const float* b1  = (const float*)d_in[5];
    const float* W2  = (const float*)d_in[6];
    const float* as2 = (const float*)d_in[7];
    const float* ad2 = (const float*)d_in[8];
    const float* b2  = (const float*)d_in[9];
    const float* W1r  = (const float*)d_in[10];
    const float* as1r = (const float*)d_in[11];
    const float* ad1r = (const float*)d_in[12];
    const float* b1r  = (const float*)d_in[13];
    const float* W2r  = (const float*)d_in[14];
    const float* as2r = (const float*)d_in[15];
    const float* ad2r = (const float*)d_in[16];
    const float* b2r  = (const float*)d_in[17];

    const int N = in_sizes[0] / 3;
    const long long E = in_sizes[1] / 2;
    const int NB8 = (N + BNODES - 1) >> BSH;
    const int NS = 2 * NB8;
    const int NB9 = (N + BN9 - 1) >> 9;

    char* w = (char*)d_ws;
    size_t o = 0;
    auto A = [&](size_t bytes) { o = (o + 255) & ~(size_t)255; size_t r = o; o += bytes; return r; };
    size_t oR4f  = A(sizeof(float4) * N);
    size_t oR4r  = A(sizeof(float4) * N);
    size_t oS1df = A(sizeof(float) * N);
    size_t oS1dr = A(sizeof(float) * N);
    size_t oP2f  = A(sizeof(float2) * N);
    size_t oS2df = A(sizeof(float) * N);
    size_t oP2r  = A(sizeof(float2) * N);
    size_t oS2dr = A(sizeof(float) * N);
    size_t oRes  = A(sizeof(float) * 2 * N);
    size_t oAoff = A(sizeof(int) * 2 * N);
    size_t oAend = A(sizeof(int) * 2 * N);
    size_t oGcur = A(sizeof(int) * NS);
    size_t oBin  = A(sizeof(unsigned) * (size_t)NS * CAP);
    (void)ws_size; (void)n_in; (void)out_size;

    float4* rec4f = (float4*)(w + oR4f);
    float4* rec4r = (float4*)(w + oR4r);
    float*  s1df = (float*)(w + oS1df);
    float*  s1dr = (float*)(w + oS1dr);
    float2* p2f  = (float2*)(w + oP2f);
    float*  s2df = (float*)(w + oS2df);
    float2* p2r  = (float2*)(w + oP2r);
    float*  s2dr = (float*)(w + oS2dr);
    float*  res  = (float*)(w + oRes);
    int*    aoff = (int*)(w + oAoff);
    int*    aend = (int*)(w + oAend);
    int*    gcur = (int*)(w + oGcur);
    unsigned* bin = (unsigned*)(w + oBin);

    dim3 gN((N + 255) / 256);

    k_prep<<<gN, 256, 0, stream>>>(x, as1, ad1, as1r, ad1r, W1, W1r,
                                   rec4f, rec4r, s1df, s1dr, gcur, NS, N);

    FP p;
    p.ei = ei; p.E = E; p.NB8 = NB8; p.NS = NS; p.N = N;
    p.gcur = gcur; p.bin = bin;
    p.rec4f = rec4f; p.s1df = s1df; p.rec4r = rec4r; p.s1dr = s1dr;
    p.b1 = b1; p.W1 = W1; p.W2 = W2; p.as2 = as2; p.ad2 = ad2;
    p.b1r = b1r; p.W1r = W1r; p.W2r = W2r; p.as2r = as2r; p.ad2r = ad2r;
    p.b2 = b2; p.b2r = b2r;
    p.p2f = p2f; p.p2r = p2r; p.s2df = s2df; p.s2dr = s2dr;
    p.res = res; p.out = (float*)d_out;

    void* args[] = { &p };
    hipError_t cerr = hipLaunchCooperativeKernel((const void*)k_fused,
                                                 dim3(2 * NB9), dim3(TPB),
                                                 args, 0, stream);
    if (cerr != hipSuccess) {
        // fallback: proven r16 pipeline on the same buffers (gcur already zeroed)
        size_t smem = sizeof(unsigned) * (size_t)NS * SLOT
                    + sizeof(int) * (size_t)NS * 2
                    + sizeof(int) * SPILLCAP * 2
                    + sizeof(unsigned) * SPILLCAP
                    + 64;
        k_scatsort<<<GB, 512, smem, stream>>>(ei, E, NB8, NS, gcur, bin);
        k_bagg1<<<dim3(NB9, 2), TPB, 0, stream>>>(bin, gcur, rec4f, s1df, rec4r, s1dr,
                                                  b1, W1, W2, as2, ad2,
                                                  b1r, W1r, W2r, as2r, ad2r,
                                                  p2f, s2df, p2r, s2dr, aoff, aend, NB8, N);
        k_agg2<<<dim3((N * 16 + 255) / 256), 256, 0, stream>>>(
            bin, aoff, aend, p2f, s2df, p2r, s2dr, b2, b2r, (float*)d_out, N);
    }
}

// Round 19
// 233.715 us; speedup vs baseline: 3.3715x; 3.3715x over previous
//
#include <hip/hip_runtime.h>
#include <math.h>

#define NSLOPE 0.2f
#define BSH 8                  // 256 nodes per scatter stream-bucket
#define BNODES 256
#define NID_MASK 0x1FFFF       // node id fits 17 bits (N <= 131072)
#define SENT 0xFFFFFFFFu
#define CAP 10240              // per-stream region capacity
#define GB 768                 // scatsort blocks (3/CU resident — measured best)
#define RE 2560                // edges per scatsort round
#define EPT 5                  // edges per thread per round (RE/512)
#define SLOT 12                // LDS slots per stream per round (mean 6.5)
#define SPILLCAP 256
#define BN9 512                // bagg1 super-bucket nodes
#define LCAP 17408             // bagg1 LDS list capacity (records)
#define BAGT 1024              // bagg1 threads
#define CPP9 9                 // bagg1 pairs per thread (ceil(LCAP/2/BAGT))

__device__ __forceinline__ float lrelu(float v) { return v > 0.f ? v : NSLOPE * v; }

// ---------------------------------------------------------------- node prep
// rec4 = {x0,x1,x2, s1s} per direction; s1d separate; zero stream cursors.
__global__ void k_prep(const float* __restrict__ x,
                       const float* __restrict__ as1, const float* __restrict__ ad1,
                       const float* __restrict__ as1r, const float* __restrict__ ad1r,
                       const float* __restrict__ W1, const float* __restrict__ W1r,
                       float4* __restrict__ rec4f, float4* __restrict__ rec4r,
                       float* __restrict__ s1df, float* __restrict__ s1dr,
                       int* __restrict__ gcur, int NS, int N) {
    int i = blockIdx.x * blockDim.x + threadIdx.x;
    if (i < NS) gcur[i] = 0;
    if (i >= N) return;
    float x0 = x[3 * i], x1 = x[3 * i + 1], x2 = x[3 * i + 2];
    float ssf = 0.f, sdf = 0.f, ssr = 0.f, sdr = 0.f;
#pragma unroll
    for (int k = 0; k < 16; k++) {
        float hf = x0 * W1[k] + x1 * W1[16 + k] + x2 * W1[32 + k];
        ssf += hf * as1[k];
        sdf += hf * ad1[k];
        float hr = x0 * W1r[k] + x1 * W1r[16 + k] + x2 * W1r[32 + k];
        ssr += hr * as1r[k];
        sdr += hr * ad1r[k];
    }
    rec4f[i] = make_float4(x0, x1, x2, ssf);
    rec4r[i] = make_float4(x0, x1, x2, ssr);
    s1df[i] = sdf; s1dr[i] = sdr;
}

// ---------------------------------------------------------------- scatter+sort (slotted)
// Per round: PHASE A loads 5 edges/thread into registers (independent global
// loads); PHASE B places the 10 records into per-stream 12-slot LDS strips
// (1 LDS atomic + 1 write each); then one EXACT global reservation per
// (round,stream) and pair-wise copy-out. Edge dtype detected inline.
__global__ void __launch_bounds__(512) k_scatsort(
        const void* __restrict__ ei, long long E,
        int NB, int NS, int* __restrict__ gcur, unsigned* __restrict__ bin) {
    extern __shared__ unsigned smem[];
    unsigned* slots = smem;                         // NS*SLOT
    int* cnt  = (int*)(slots + (size_t)NS * SLOT);  // NS
    int* gpos = cnt + NS;                           // NS
    int* spill_s = gpos + NS;                       // SPILLCAP
    int* spill_p = spill_s + SPILLCAP;              // SPILLCAP
    unsigned* spill_r = (unsigned*)(spill_p + SPILLCAP); // SPILLCAP
    int* spn = (int*)(spill_r + SPILLCAP);          // 1
    __shared__ int flagsm;

    int t = threadIdx.x;
    if (t < 64) {   // dtype detect: all u64 words < 2^32 -> int64 layout
        const unsigned long long* p = (const unsigned long long*)ei;
        bool bad = false;
#pragma unroll
        for (int i = 0; i < 4; i++)
            if (p[t * 4 + i] >= (1ull << 32)) bad = true;
        unsigned long long mask = __ballot(bad);
        if (t == 0) flagsm = (mask == 0ull) ? 1 : 0;
    }
    __syncthreads();
    int fl = flagsm;
    long long chunk = (E + GB - 1) / GB;
    long long cstart = (long long)blockIdx.x * chunk;
    long long cend = cstart + chunk; if (cend > E) cend = E;

    for (long long rs = cstart; rs < cend; rs += RE) {
        int ne = (int)min((long long)RE, cend - rs);
        for (int c = t; c < NS; c += 512) cnt[c] = 0;
        if (t == 0) *spn = 0;
        // PHASE A: load edges into registers
        int eu[EPT], ev[EPT];
#pragma unroll
        for (int k = 0; k < EPT; k++) {
            int idx = t + k * 512;
            eu[k] = -1;
            if (idx < ne) {
                long long i = rs + idx;
                if (fl) { const long long* p = (const long long*)ei;
                          eu[k] = (int)p[i]; ev[k] = (int)p[E + i]; }
                else    { const int* p = (const int*)ei;
                          eu[k] = p[i]; ev[k] = p[E + i]; }
            }
        }
        __syncthreads();
        // PHASE B: place records
#pragma unroll
        for (int k = 0; k < EPT; k++) {
            if (eu[k] >= 0) {
                int u = eu[k], v = ev[k];
                unsigned r0 = (unsigned)u | ((unsigned)(v & (BNODES - 1)) << 17);
                int s0 = v >> BSH;
                unsigned r1 = (unsigned)v | ((unsigned)(u & (BNODES - 1)) << 17);
                int s1 = NB + (u >> BSH);
                int p0 = atomicAdd(&cnt[s0], 1);
                if (p0 < SLOT) slots[s0 * SLOT + p0] = r0;
                else { int sp = atomicAdd(spn, 1); if (sp < SPILLCAP) { spill_s[sp] = s0; spill_p[sp] = p0; spill_r[sp] = r0; } }
                int p1 = atomicAdd(&cnt[s1], 1);
                if (p1 < SLOT) slots[s1 * SLOT + p1] = r1;
                else { int sp = atomicAdd(spn, 1); if (sp < SPILLCAP) { spill_s[sp] = s1; spill_p[sp] = p1; spill_r[sp] = r1; } }
            }
        }
        __syncthreads();
        for (int c = t; c < NS; c += 512) {
            int n = cnt[c];
            gpos[c] = n ? atomicAdd(&gcur[c], n) : 0;   // EXACT reservation
        }
        __syncthreads();
        for (int c = t; c < NS; c += 512) {
            int n = cnt[c];
            if (!n) continue;
            int g = gpos[c];
            long long b = (long long)c * CAP;
            int m = n < SLOT ? n : SLOT;       // records present in the strip
            if (g + n <= CAP) {
                int j = 0;
                if (g & 1) { bin[b + g] = slots[c * SLOT]; j = 1; }
                for (; j + 2 <= m; j += 2)
                    *(uint2*)(bin + b + g + j) =
                        make_uint2(slots[c * SLOT + j], slots[c * SLOT + j + 1]);
                if (j < m) bin[b + g + j] = slots[c * SLOT + j];
            }
        }
        int nsp = *spn; if (nsp > SPILLCAP) nsp = SPILLCAP;
        for (int i = t; i < nsp; i += 512) {
            int s = spill_s[i];
            int off = gpos[s] + spill_p[i];
            if (off < CAP) bin[(long long)s * CAP + off] = spill_r[i];
        }
        __syncthreads();
    }
}

// ---------------------------------------------------------------- fused sort+agg, layer 1
// One block per (512-node super-bucket, dir), 1024 threads. Loads the two
// adjacent 256-node stream regions (second region: +256 on the local-node
// field; half-valid last pairs masked), LDS count + wave-shuffle scan +
// count-sort by local node (512 bins), aggregates with 2 private-register
// lanes per node (plain-exp softmax, rank-3 trick), then uint2-dumps the
// node-sorted list back at the first region's base + [start,end) arrays.
__global__ void __launch_bounds__(BAGT, 8) k_bagg1(
        unsigned* __restrict__ bin, const int* __restrict__ gcur,
        const float4* __restrict__ rec4f, const float* __restrict__ s1df,
        const float4* __restrict__ rec4r, const float* __restrict__ s1dr,
        const float* __restrict__ b1, const float* __restrict__ W1,
        const float* __restrict__ W2,
        const float* __restrict__ as2, const float* __restrict__ ad2,
        const float* __restrict__ b1r, const float* __restrict__ W1r,
        const float* __restrict__ W2r,
        const float* __restrict__ as2r, const float* __restrict__ ad2r,
        float2* __restrict__ p2f, float* __restrict__ s2df,
        float2* __restrict__ p2r, float* __restrict__ s2dr,
        int* __restrict__ aoff, int* __restrict__ aend, int NB8, int N) {
    int bb = blockIdx.x, dir = blockIdx.y;
    const float4* rec4 = dir ? rec4r : rec4f;
    const float* s1d = dir ? s1dr : s1df;
    const float* b1_ = dir ? b1r : b1;
    const float* W1_ = dir ? W1r : W1;
    const float* W2_ = dir ? W2r : W2;
    float as2v = dir ? as2r[0] : as2[0];
    float ad2v = dir ? ad2r[0] : ad2[0];
    float2* p2 = dir ? p2r : p2f;
    float* s2d = dir ? s2dr : s2df;

    int c0 = dir * NB8 + 2 * bb;
    bool c1ok = (2 * bb + 1) < NB8;
    long long base = (long long)c0 * CAP;
    int n0 = gcur[c0]; if (n0 > CAP) n0 = CAP;
    int n1 = c1ok ? gcur[c0 + 1] : 0; if (n1 > CAP) n1 = CAP;
    int np0 = (n0 + 1) >> 1, np1 = (n1 + 1) >> 1;
    if (np0 > LCAP / 2) np0 = LCAP / 2;
    if (np0 + np1 > LCAP / 2) np1 = LCAP / 2 - np0;
    int nptot = np0 + np1;
    int v0 = bb << 9;
    int nv = N - v0; if (nv > BN9) nv = BN9;

    __shared__ int cnt[BN9];
    __shared__ int loff[BN9];
    __shared__ int segtot[8];
    __shared__ unsigned lds_u[LCAP];
    int t = threadIdx.x;

    const uint2* bp0 = (const uint2*)(bin + base);
    const uint2* bp1 = (const uint2*)(bin + base) + CAP / 2;
    uint2 recs[CPP9];
#pragma unroll
    for (int k = 0; k < CPP9; k++) {
        int i = t + k * BAGT;
        uint2 r = make_uint2(SENT, SENT);
        if (i < np0) {
            r = bp0[i];                           // r.x valid (2i < n0)
            if (2 * i + 1 >= n0) r.y = SENT;      // mask garbage half
        } else if (i < nptot) {
            int i1 = i - np0;
            r = bp1[i1];
            if (2 * i1 + 1 >= n1) r.y = SENT;
            r.x += (256u << 17);                  // local += 256
            if (r.y != SENT) r.y += (256u << 17);
        }
        recs[k] = r;
    }
    if (t < BN9) cnt[t] = 0;
    __syncthreads();
#pragma unroll
    for (int k = 0; k < CPP9; k++) {
        if (recs[k].x != SENT) atomicAdd(&cnt[recs[k].x >> 17], 1);
        if (recs[k].y != SENT) atomicAdd(&cnt[recs[k].y >> 17], 1);
    }
    __syncthreads();
    // wave-shuffle exclusive scan over 512 counts (waves 0..7)
    if (t < BN9) {
        int lane = t & 63, wv = t >> 6;
        int val = cnt[t];
        int incl = val;
#pragma unroll
        for (int od = 1; od < 64; od <<= 1) {
            int up = __shfl_up(incl, od);
            if (lane >= od) incl += up;
        }
        if (lane == 63) segtot[wv] = incl;
        loff[t] = incl - val;
    }
    __syncthreads();
    if (t < BN9) {
        int wv = t >> 6;
        int offs = 0;
#pragma unroll
        for (int j = 0; j < 8; j++) offs += (j < wv) ? segtot[j] : 0;
        int ex = loff[t] + offs;
        loff[t] = ex;
        cnt[t] = ex;               // scatter cursor -> list end
    }
    __syncthreads();
#pragma unroll
    for (int k = 0; k < CPP9; k++) {
        if (recs[k].x != SENT) {
            int q = atomicAdd(&cnt[recs[k].x >> 17], 1);
            lds_u[q] = recs[k].x & NID_MASK;
        }
        if (recs[k].y != SENT) {
            int q = atomicAdd(&cnt[recs[k].y >> 17], 1);
            lds_u[q] = recs[k].y & NID_MASK;
        }
    }
    __syncthreads();
    // aggregate: 2 lanes per node
    int node = t >> 1, lane = t & 1;
    float sdv = (node < nv) ? s1d[v0 + node] : 0.f;
    float d = 0.f, a0 = 0.f, a1 = 0.f, a2 = 0.f;
    if (node < nv) {
        int ls = loff[node], le = cnt[node];
        for (int pos = ls + lane; pos < le; pos += 2) {
            unsigned u = lds_u[pos];
            float4 r = rec4[u];
            float w = __expf(lrelu(r.w + sdv));
            d += w; a0 += w * r.x; a1 += w * r.y; a2 += w * r.z;
        }
    }
    d  += __shfl_xor(d, 1);
    a0 += __shfl_xor(a0, 1);
    a1 += __shfl_xor(a1, 1);
    a2 += __shfl_xor(a2, 1);
    if (lane == 0 && node < nv) {
        int v = v0 + node;
        float4 r = rec4[v];
        float w = __expf(lrelu(r.w + sdv));    // self loop
        float dd = d + w;
        float inv = 1.f / (dd + 1e-16f);
        float m0 = (a0 + w * r.x) * inv;
        float m1 = (a1 + w * r.y) * inv;
        float m2 = (a2 + w * r.z) * inv;
        float h2v = 0.f;
#pragma unroll
        for (int k = 0; k < 16; k++) {
            float o = m0 * W1_[k] + m1 * W1_[16 + k] + m2 * W1_[32 + k] + b1_[k];
            o = fmaxf(o, 0.f);
            h2v += o * W2_[k];
        }
        p2[v] = make_float2(h2v, h2v * as2v);
        s2d[v] = h2v * ad2v;
    }
    // dump sorted list back in place as pairs (odd tail SENT-padded)
    int nreal = (nv > 0) ? cnt[nv - 1] : 0;
    if (t == 0 && (nreal & 1)) lds_u[nreal] = SENT;
    __syncthreads();
    int ndp = (nreal + 1) >> 1;
    uint2* bq = (uint2*)(bin + base);
    for (int i = t; i < ndp; i += BAGT)
        bq[i] = make_uint2(lds_u[2 * i], lds_u[2 * i + 1]);
    if (t < nv) {
        aoff[dir * N + v0 + t] = (int)(base + loff[t]);
        aend[dir * N + v0 + t] = (int)(base + cnt[t]);
    }
}

// ---------------------------------------------------------------- layer-2 agg (sort-free)
// 16 lanes per node, 2x ILP, reads the node-sorted bin + per-node [start,end).
__global__ void k_agg2(const unsigned* __restrict__ bin,
                       const int* __restrict__ aoff, const int* __restrict__ aend,
                       const float2* __restrict__ p2f, const float* __restrict__ s2df,
                       const float2* __restrict__ p2r, const float* __restrict__ s2dr,
                       const float* __restrict__ b2, const float* __restrict__ b2r,
                       float* __restrict__ out, int N) {
    int tid = blockIdx.x * blockDim.x + threadIdx.x;
    int v = tid >> 4;
    int lane = tid & 15;
    if (v >= N) return;
    float res[2];
#pragma unroll
    for (int dir = 0; dir < 2; dir++) {
        const float2* p2 = dir ? p2r : p2f;
        const float* s2d = dir ? s2dr : s2df;
        float bias = dir ? b2r[0] : b2[0];
        float sd = s2d[v];
        int st = aoff[dir * N + v], en = aend[dir * N + v];
        float d = 0.f, a = 0.f;
        if (lane == 0) {  // self loop
            float2 ts = p2[v];
            float w = __expf(lrelu(ts.y + sd));
            d = w; a = w * ts.x;
        }
        int j = st + lane;
        for (; j + 16 < en; j += 32) {
            unsigned u0 = __builtin_nontemporal_load(bin + j);
            unsigned u1 = __builtin_nontemporal_load(bin + j + 16);
            float2 t0 = p2[u0];
            float2 t1 = p2[u1];
            float w0 = __expf(lrelu(t0.y + sd));
            float w1 = __expf(lrelu(t1.y + sd));
            d += w0 + w1;
            a += w0 * t0.x + w1 * t1.x;
        }
        for (; j < en; j += 16) {
            unsigned u = __builtin_nontemporal_load(bin + j);
            float2 t = p2[u];
            float w = __expf(lrelu(t.y + sd));
            d += w;
            a += w * t.x;
        }
#pragma unroll
        for (int mask = 1; mask < 16; mask <<= 1) {
            d += __shfl_xor(d, mask);
            a += __shfl_xor(a, mask);
        }
        res[dir] = a / (d + 1e-16f) + bias;
    }
    if (lane == 0) out[v] = 0.5f * (res[0] + res[1]);
}

// ================================================================ launch
extern "C" void kernel_launch(void* const* d_in, const int* in_sizes, int n_in,
                              void* d_out, int out_size, void* d_ws, size_t ws_size,
                              hipStream_t stream) {
    const float* x   = (const float*)d_in[0];
    const void*  ei  = d_in[1];
    const float* W1  = (const float*)d_in[2];
    const float* as1 = (const float*)d_in[3];
    const float* ad1 = (const float*)d_in[4];
    const float* b1  = (const float*)d_in[5];
    const float* W2  = (const float*)d_in[6];
    const float* as2 = (const float*)d_in[7];
    const float* ad2 = (const float*)d_in[8];
    const float* b2  = (const float*)d_in[9];
    const float* W1r  = (const float*)d_in[10];
    const float* as1r = (const float*)d_in[11];
    const float* ad1r = (const float*)d_in[12];
    const float* b1r  = (const float*)d_in[13];
    const float* W2r  = (const float*)d_in[14];
    const float* as2r = (const float*)d_in[15];
    const float* ad2r = (const float*)d_in[16];
    const float* b2r  = (const float*)d_in[17];

    const int N = in_sizes[0] / 3;
    const long long E = in_sizes[1] / 2;
    const int NB8 = (N + BNODES - 1) >> BSH;  // 256-node buckets per direction
    const int NS = 2 * NB8;                   // total scatter streams
    const int NB9 = (N + BN9 - 1) >> 9;       // 512-node super-buckets

    char* w = (char*)d_ws;
    size_t o = 0;
    auto A = [&](size_t bytes) { o = (o + 255) & ~(size_t)255; size_t r = o; o += bytes; return r; };
    size_t oR4f  = A(sizeof(float4) * N);
    size_t oR4r  = A(sizeof(float4) * N);
    size_t oS1df = A(sizeof(float) * N);
    size_t oS1dr = A(sizeof(float) * N);
    size_t oP2f  = A(sizeof(float2) * N);
    size_t oS2df = A(sizeof(float) * N);
    size_t oP2r  = A(sizeof(float2) * N);
    size_t oS2dr = A(sizeof(float) * N);
    size_t oAoff = A(sizeof(int) * 2 * N);
    size_t oAend = A(sizeof(int) * 2 * N);
    size_t oGcur = A(sizeof(int) * NS);
    size_t oBin  = A(sizeof(unsigned) * (size_t)NS * CAP);
    (void)ws_size; (void)n_in; (void)out_size;

    float4* rec4f = (float4*)(w + oR4f);
    float4* rec4r = (float4*)(w + oR4r);
    float*  s1df = (float*)(w + oS1df);
    float*  s1dr = (float*)(w + oS1dr);
    float2* p2f  = (float2*)(w + oP2f);
    float*  s2df = (float*)(w + oS2df);
    float2* p2r  = (float2*)(w + oP2r);
    float*  s2dr = (float*)(w + oS2dr);
    int*    aoff = (int*)(w + oAoff);
    int*    aend = (int*)(w + oAend);
    int*    gcur = (int*)(w + oGcur);
    unsigned* bin = (unsigned*)(w + oBin);

    dim3 gN((N + 255) / 256);
    dim3 gAgg1(NB9, 2);
    dim3 gAgg2((N * 16 + 255) / 256);

    size_t smem = sizeof(unsigned) * (size_t)NS * SLOT
                + sizeof(int) * (size_t)NS * 2
                + sizeof(int) * SPILLCAP * 2
                + sizeof(unsigned) * SPILLCAP
                + 64;

    k_prep<<<gN, 256, 0, stream>>>(x, as1, ad1, as1r, ad1r, W1, W1r,
                                   rec4f, rec4r, s1df, s1dr, gcur, NS, N);
    k_scatsort<<<GB, 512, smem, stream>>>(ei, E, NB8, NS, gcur, bin);
    k_bagg1<<<gAgg1, BAGT, 0, stream>>>(bin, gcur, rec4f, s1df, rec4r, s1dr,
                                        b1, W1, W2, as2, ad2,
                                        b1r, W1r, W2r, as2r, ad2r,
                                        p2f, s2df, p2r, s2dr, aoff, aend, NB8, N);
    k_agg2<<<gAgg2, 256, 0, stream>>>(bin, aoff, aend, p2f, s2df, p2r, s2dr,
                                      b2, b2r, (float*)d_out, N);
}